// Round 7
// baseline (342.918 us; speedup 1.0000x reference)
//
#include <hip/hip_runtime.h>
#include <hip/hip_bf16.h>

using bf16x8  = __attribute__((ext_vector_type(8))) __bf16;
using f32x4   = __attribute__((ext_vector_type(4))) float;
using ushortx8 = __attribute__((ext_vector_type(8))) unsigned short;
typedef unsigned short ushort_t;

#define M_DIM 16384
#define K_DIM 4096
#define N_DIM 1024

#define BARR() __builtin_amdgcn_s_barrier()
// asm global load: issue-early staging that cannot be sunk to its use site
// (volatile asm keeps program position); vmcnt bookkeeping is manual.
#define GLOAD(q, p) asm volatile("global_load_dwordx4 %0, %1, off" : "=v"(q) : "v"(p))

__device__ __forceinline__ unsigned short f2bf(float f) {
  __hip_bfloat16 h = __float2bfloat16(f);  // RNE
  return *reinterpret_cast<unsigned short*>(&h);
}

__device__ __forceinline__ float snap(float a) {
  float q = 0.0f;
  q += (a > 0.25f) ? 0.5f : 0.0f;
  q += (a > 0.75f) ? 0.5f : 0.0f;
  q += (a > 1.25f) ? 0.5f : 0.0f;
  q += (a > 1.75f) ? 0.5f : 0.0f;
  q += (a > 2.5f)  ? 1.0f : 0.0f;
  q += (a > 3.5f)  ? 1.0f : 0.0f;
  q += (a > 5.0f)  ? 2.0f : 0.0f;
  return q;
}

__device__ __forceinline__ unsigned short qdq(float xv, float rs, float scale) {
  float xs = xv * rs;
  float q  = copysignf(snap(fabsf(xs)), xs);
  return f2bf(q * scale);
}

__global__ __launch_bounds__(256) void quant_kernel(const float* __restrict__ x,
                                                    unsigned short* __restrict__ dq) {
  const int wid = (blockIdx.x << 2) + (threadIdx.x >> 6);
  const int l   = threadIdx.x & 63;
  const int sub = l >> 4, t = l & 15;
  const size_t base = ((size_t)wid * 4 + sub) * 128;
  const float4* px = reinterpret_cast<const float4*>(x + base);
  float4 v0 = px[t];
  float4 v1 = px[16 + t];
  float amax = fmaxf(fmaxf(fmaxf(fabsf(v0.x), fabsf(v0.y)), fmaxf(fabsf(v0.z), fabsf(v0.w))),
                     fmaxf(fmaxf(fabsf(v1.x), fabsf(v1.y)), fmaxf(fabsf(v1.z), fabsf(v1.w))));
  #pragma unroll
  for (int m = 1; m < 16; m <<= 1) amax = fmaxf(amax, __shfl_xor(amax, m, 64));
  float scale = amax / 6.0f;
  if (scale == 0.0f) scale = 1.0f;
  const float rs = 1.0f / scale;
  ushort4 o0, o1;
  o0.x = qdq(v0.x, rs, scale); o0.y = qdq(v0.y, rs, scale);
  o0.z = qdq(v0.z, rs, scale); o0.w = qdq(v0.w, rs, scale);
  o1.x = qdq(v1.x, rs, scale); o1.y = qdq(v1.y, rs, scale);
  o1.z = qdq(v1.z, rs, scale); o1.w = qdq(v1.w, rs, scale);
  reinterpret_cast<ushort4*>(dq + base)[t]      = o0;
  reinterpret_cast<ushort4*>(dq + base)[16 + t] = o1;
}

__global__ __launch_bounds__(256) void wconv_kernel(const float* __restrict__ w,
                                                    unsigned short* __restrict__ o) {
  const int n4 = (N_DIM * K_DIM) / 4;
  for (int i = blockIdx.x * 256 + threadIdx.x; i < n4; i += gridDim.x * 256) {
    float4 v = reinterpret_cast<const float4*>(w)[i];
    ushort4 u;
    u.x = f2bf(v.x); u.y = f2bf(v.y); u.z = f2bf(v.z); u.w = f2bf(v.w);
    reinterpret_cast<ushort4*>(o)[i] = u;
  }
}

__device__ __forceinline__ bf16x8 lds_ld(const ushort_t* p) {
  return *reinterpret_cast<const bf16x8*>(p);
}

// Prologue-only staging: plain load + plain ds_write (compiler-managed waits).
__device__ __forceinline__ void pstage(ushort_t (&slot)[8192], const ushort_t* g0,
                                       const ushort_t* g1, int dsw) {
  ushortx8 q0 = *reinterpret_cast<const ushortx8*>(g0);
  ushortx8 q1 = *reinterpret_cast<const ushortx8*>(g1);
  *reinterpret_cast<ushortx8*>(&slot[dsw])        = q0;
  *reinterpret_cast<ushortx8*>(&slot[4096 + dsw]) = q1;
}

// One K-tile (BK=64), reg-staged: 4 phases, 1 barrier each.
// Phase k: [vmcnt(2); ds_write half-tile staged 2 phases ago] [asm-issue 2
// global loads for +2-phase target] [ds_reads ahead] [MFMA] [lgkmcnt(0)] [bar].
// vmcnt count: at every write point exactly 2 newer staging loads are
// outstanding (except t62-ph2: 0). All MFMA/read waits are SSA-precise.
template<bool W12, bool L12, bool W34, bool L34>
__device__ __forceinline__ void tile_iter(
    int t,
    ushort_t (&rA)[8192],  ushort_t (&rB)[8192],
    ushort_t (&dB1)[8192], ushort_t (&dA1)[8192],
    ushort_t (&dB0)[8192], ushort_t (&dA0)[8192],
    int dsw,
    const int (&roA)[8], const int (&roB)[4], int swz0, int swz1,
    const ushort_t* pa0, const ushort_t* pa1,
    const ushort_t* pb0, const ushort_t* pb1,
    ushortx8 (&gBa)[2], ushortx8 (&gBb)[2],
    ushortx8 (&gAa)[2], ushortx8 (&gAb)[2],
    f32x4 (&acc)[8][4]) {
  bf16x8 aL0[4], aL1[4], aH0[4], aH1[4], b0[4], b1[4];

  // tile-start reads: A(m0-3) + B(n0-1)
  #pragma unroll
  for (int i = 0; i < 4; ++i) {
    aL0[i] = lds_ld(&rA[roA[i] + swz0]);
    aL1[i] = lds_ld(&rA[roA[i] + swz1]);
  }
  #pragma unroll
  for (int n = 0; n < 2; ++n) {
    b0[n] = lds_ld(&rB[roB[n] + swz0]);
    b1[n] = lds_ld(&rB[roB[n] + swz1]);
  }

  // ---- phase 1: write B1(t+1); issue B0(t+2); read b23; MFMA aL x b01
  if constexpr (W12) {
    asm volatile("s_waitcnt vmcnt(2)" ::: "memory");
    *reinterpret_cast<ushortx8*>(&dB1[dsw])        = gBa[0];
    *reinterpret_cast<ushortx8*>(&dB1[4096 + dsw]) = gBa[1];
  }
  if constexpr (L12) {
    GLOAD(gBb[0], pb0 + (size_t)(t + 2) * 64);
    GLOAD(gBb[1], pb1 + (size_t)(t + 2) * 64);
  }
  #pragma unroll
  for (int n = 2; n < 4; ++n) {
    b0[n] = lds_ld(&rB[roB[n] + swz0]);
    b1[n] = lds_ld(&rB[roB[n] + swz1]);
  }
  __builtin_amdgcn_s_setprio(1);
  #pragma unroll
  for (int i = 0; i < 4; ++i)
    #pragma unroll
    for (int n = 0; n < 2; ++n) {
      acc[i][n] = __builtin_amdgcn_mfma_f32_16x16x32_bf16(aL0[i], b0[n], acc[i][n], 0, 0, 0);
      acc[i][n] = __builtin_amdgcn_mfma_f32_16x16x32_bf16(aL1[i], b1[n], acc[i][n], 0, 0, 0);
    }
  __builtin_amdgcn_s_setprio(0);
  if constexpr (W12) asm volatile("s_waitcnt lgkmcnt(0)" ::: "memory");
  BARR();

  // ---- phase 2: write A1(t+1); issue A0(t+2); read aH; MFMA aL x b23
  if constexpr (W12) {
    asm volatile("s_waitcnt vmcnt(%0)" :: "i"(W34 ? 2 : 0) : "memory");
    *reinterpret_cast<ushortx8*>(&dA1[dsw])        = gAa[0];
    *reinterpret_cast<ushortx8*>(&dA1[4096 + dsw]) = gAa[1];
  }
  if constexpr (L12) {
    GLOAD(gAb[0], pa0 + (size_t)(t + 2) * 64);
    GLOAD(gAb[1], pa1 + (size_t)(t + 2) * 64);
  }
  #pragma unroll
  for (int i = 0; i < 4; ++i) {
    aH0[i] = lds_ld(&rA[roA[4 + i] + swz0]);
    aH1[i] = lds_ld(&rA[roA[4 + i] + swz1]);
  }
  __builtin_amdgcn_s_setprio(1);
  #pragma unroll
  for (int i = 0; i < 4; ++i)
    #pragma unroll
    for (int n = 2; n < 4; ++n) {
      acc[i][n] = __builtin_amdgcn_mfma_f32_16x16x32_bf16(aL0[i], b0[n], acc[i][n], 0, 0, 0);
      acc[i][n] = __builtin_amdgcn_mfma_f32_16x16x32_bf16(aL1[i], b1[n], acc[i][n], 0, 0, 0);
    }
  __builtin_amdgcn_s_setprio(0);
  if constexpr (W12) asm volatile("s_waitcnt lgkmcnt(0)" ::: "memory");
  BARR();

  // ---- phase 3: write B0(t+2); issue B1(t+2); MFMA aH x b23
  if constexpr (W34) {
    asm volatile("s_waitcnt vmcnt(2)" ::: "memory");
    *reinterpret_cast<ushortx8*>(&dB0[dsw])        = gBb[0];
    *reinterpret_cast<ushortx8*>(&dB0[4096 + dsw]) = gBb[1];
  }
  if constexpr (L34) {
    GLOAD(gBa[0], pb0 + (size_t)128 * K_DIM + (size_t)(t + 2) * 64);
    GLOAD(gBa[1], pb1 + (size_t)128 * K_DIM + (size_t)(t + 2) * 64);
  }
  __builtin_amdgcn_s_setprio(1);
  #pragma unroll
  for (int i = 0; i < 4; ++i)
    #pragma unroll
    for (int n = 2; n < 4; ++n) {
      acc[4 + i][n] = __builtin_amdgcn_mfma_f32_16x16x32_bf16(aH0[i], b0[n], acc[4 + i][n], 0, 0, 0);
      acc[4 + i][n] = __builtin_amdgcn_mfma_f32_16x16x32_bf16(aH1[i], b1[n], acc[4 + i][n], 0, 0, 0);
    }
  __builtin_amdgcn_s_setprio(0);
  if constexpr (W34) asm volatile("s_waitcnt lgkmcnt(0)" ::: "memory");
  BARR();

  // ---- phase 4: write A0(t+2); issue A1(t+2); MFMA aH x b01
  if constexpr (W34) {
    asm volatile("s_waitcnt vmcnt(2)" ::: "memory");
    *reinterpret_cast<ushortx8*>(&dA0[dsw])        = gAb[0];
    *reinterpret_cast<ushortx8*>(&dA0[4096 + dsw]) = gAb[1];
  }
  if constexpr (L34) {
    GLOAD(gAa[0], pa0 + (size_t)128 * K_DIM + (size_t)(t + 2) * 64);
    GLOAD(gAa[1], pa1 + (size_t)128 * K_DIM + (size_t)(t + 2) * 64);
  }
  __builtin_amdgcn_s_setprio(1);
  #pragma unroll
  for (int i = 0; i < 4; ++i)
    #pragma unroll
    for (int n = 0; n < 2; ++n) {
      acc[4 + i][n] = __builtin_amdgcn_mfma_f32_16x16x32_bf16(aH0[i], b0[n], acc[4 + i][n], 0, 0, 0);
      acc[4 + i][n] = __builtin_amdgcn_mfma_f32_16x16x32_bf16(aH1[i], b1[n], acc[4 + i][n], 0, 0, 0);
    }
  __builtin_amdgcn_s_setprio(0);
  if constexpr (W34) asm volatile("s_waitcnt lgkmcnt(0)" ::: "memory");
  BARR();
}

template<int WM, int WH>
__device__ __forceinline__ void krun(
    ushort_t (&sA0p0)[8192], ushort_t (&sA0p1)[8192],
    ushort_t (&sA1p0)[8192], ushort_t (&sA1p1)[8192],
    ushort_t (&sB0p0)[8192], ushort_t (&sB0p1)[8192],
    ushort_t (&sB1p0)[8192], ushort_t (&sB1p1)[8192],
    int dsw, const int (&roA)[8], const int (&roB)[4], int swz0, int swz1,
    const ushort_t* pa0, const ushort_t* pa1,
    const ushort_t* pb0, const ushort_t* pb1,
    f32x4 (&acc)[8][4]) {
  ushort_t (&rAp0)[8192] = WM ? sA1p0 : sA0p0;
  ushort_t (&rAp1)[8192] = WM ? sA1p1 : sA0p1;
  ushort_t (&rBp0)[8192] = WH ? sB1p0 : sB0p0;
  ushort_t (&rBp1)[8192] = WH ? sB1p1 : sB0p1;

  ushortx8 gBa[2], gBb[2], gAa[2], gAb[2];

  // Prologue: tile0 all 4 slots + tile1 half0 (serial, compiler-managed);
  // then drain vmcnt so the asm-load ledger starts at 0; then asm-preload
  // B1(1)/A1(1) into regs (outstanding = 4 entering tile 0).
  pstage(sB0p0, pb0, pb1, dsw);
  pstage(sA0p0, pa0, pa1, dsw);
  pstage(sB1p0, pb0 + (size_t)128 * K_DIM, pb1 + (size_t)128 * K_DIM, dsw);
  pstage(sA1p0, pa0 + (size_t)128 * K_DIM, pa1 + (size_t)128 * K_DIM, dsw);
  pstage(sB0p1, pb0 + 64, pb1 + 64, dsw);
  pstage(sA0p1, pa0 + 64, pa1 + 64, dsw);
  asm volatile("s_waitcnt vmcnt(0)" ::: "memory");
  GLOAD(gBa[0], pb0 + (size_t)128 * K_DIM + 64);
  GLOAD(gBa[1], pb1 + (size_t)128 * K_DIM + 64);
  GLOAD(gAa[0], pa0 + (size_t)128 * K_DIM + 64);
  GLOAD(gAa[1], pa1 + (size_t)128 * K_DIM + 64);
  asm volatile("s_waitcnt lgkmcnt(0)" ::: "memory");
  BARR();

  for (int t = 0; t < 62; t += 2) {
    tile_iter<true, true, true, true>(t,     rAp0, rBp0, sB1p1, sA1p1, sB0p0, sA0p0,
        dsw, roA, roB, swz0, swz1, pa0, pa1, pb0, pb1, gBa, gBb, gAa, gAb, acc);
    tile_iter<true, true, true, true>(t + 1, rAp1, rBp1, sB1p0, sA1p0, sB0p1, sA0p1,
        dsw, roA, roB, swz0, swz1, pa0, pa1, pb0, pb1, gBa, gBb, gAa, gAb, acc);
  }
  tile_iter<true, false, false, false>(62, rAp0, rBp0, sB1p1, sA1p1, sB0p0, sA0p0,
      dsw, roA, roB, swz0, swz1, pa0, pa1, pb0, pb1, gBa, gBb, gAa, gAb, acc);
  tile_iter<false, false, false, false>(63, rAp1, rBp1, sB1p0, sA1p0, sB0p1, sA0p1,
      dsw, roA, roB, swz0, swz1, pa0, pa1, pb0, pb1, gBa, gBb, gAa, gAb, acc);
}

// 256x256 tile, BK=64, 8 waves (2M x 4N), reg-staged 4-barrier/tile pipeline,
// XOR swizzle. A = deq [M,K], B = W [N,K] (both row-major bf16).
__global__ __launch_bounds__(512, 2) void gemm256(const ushort_t* __restrict__ A,
                                                  const ushort_t* __restrict__ B,
                                                  const float* __restrict__ bias,
                                                  float* __restrict__ C) {
  __shared__ ushort_t sA0p0[8192], sA0p1[8192], sA1p0[8192], sA1p1[8192];
  __shared__ ushort_t sB0p0[8192], sB0p1[8192], sB1p0[8192], sB1p1[8192];
  const int tid  = threadIdx.x;
  const int wid  = tid >> 6, lane = tid & 63;
  const int r    = lane & 15, h = lane >> 4;
  const int wm   = wid >> 2, wn = wid & 3;
  const int bn   = blockIdx.x, bm = blockIdx.y;

  const int x7   = lane & 7;
  const int swz0 = ((h) ^ x7) << 3;
  const int swz1 = ((4 | h) ^ x7) << 3;
  int roA[8], roB[4];
  #pragma unroll
  for (int m = 0; m < 8; ++m) roA[m] = (m * 16 + r) * 64;
  #pragma unroll
  for (int n = 0; n < 4; ++n) roB[n] = ((wn & 1) * 64 + n * 16 + r) * 64;

  const int srow0 = tid >> 3;
  const int cst   = ((tid & 7) ^ (srow0 & 7)) << 3;
  const int dsw   = tid * 8;                        // ushorts: lane-linear 16B chunks
  const ushort_t* pa0 = A + (size_t)(bm * 256 + srow0) * K_DIM + cst;
  const ushort_t* pa1 = A + (size_t)(bm * 256 + 64 + srow0) * K_DIM + cst;
  const ushort_t* pb0 = B + (size_t)(bn * 256 + srow0) * K_DIM + cst;
  const ushort_t* pb1 = B + (size_t)(bn * 256 + 64 + srow0) * K_DIM + cst;

  f32x4 acc[8][4];
  #pragma unroll
  for (int m = 0; m < 8; ++m)
    #pragma unroll
    for (int n = 0; n < 4; ++n) acc[m][n] = (f32x4){0.f, 0.f, 0.f, 0.f};

  const int wh = wn >> 1;
  if (wm == 0) {
    if (wh == 0) krun<0, 0>(sA0p0, sA0p1, sA1p0, sA1p1, sB0p0, sB0p1, sB1p0, sB1p1,
                            dsw, roA, roB, swz0, swz1, pa0, pa1, pb0, pb1, acc);
    else         krun<0, 1>(sA0p0, sA0p1, sA1p0, sA1p1, sB0p0, sB0p1, sB1p0, sB1p1,
                            dsw, roA, roB, swz0, swz1, pa0, pa1, pb0, pb1, acc);
  } else {
    if (wh == 0) krun<1, 0>(sA0p0, sA0p1, sA1p0, sA1p1, sB0p0, sB0p1, sB1p0, sB1p1,
                            dsw, roA, roB, swz0, swz1, pa0, pa1, pb0, pb1, acc);
    else         krun<1, 1>(sA0p0, sA0p1, sA1p0, sA1p1, sB0p0, sB0p1, sB1p0, sB1p1,
                            dsw, roA, roB, swz0, swz1, pa0, pa1, pb0, pb1, acc);
  }

  // Epilogue: C/D layout col=lane&15, row=(lane>>4)*4+reg  [m89/m91]
  const int orow = bm * 256 + wm * 128;
  const int ocol = bn * 256 + wn * 64;
  #pragma unroll
  for (int n = 0; n < 4; ++n) {
    const int col = ocol + n * 16 + r;
    const float bv = bias[col];
    #pragma unroll
    for (int m = 0; m < 8; ++m) {
      const int rb = orow + m * 16 + h * 4;
      #pragma unroll
      for (int j = 0; j < 4; ++j)
        C[(size_t)(rb + j) * N_DIM + col] = acc[m][n][j] + bv;
    }
  }
}

// Emergency fallback if ws is too small: fused fp32, slow but correct.
__global__ __launch_bounds__(256) void fused_naive(const float* __restrict__ x,
                                                   const float* __restrict__ w,
                                                   const float* __restrict__ bias,
                                                   float* __restrict__ out) {
  __shared__ float xq[K_DIM];
  const int row = blockIdx.x;
  const float* xr = x + (size_t)row * K_DIM;
  const int t = threadIdx.x;
  const int g = t >> 3, s = t & 7;
  float vals[16];
  float amax = 0.f;
  #pragma unroll
  for (int i = 0; i < 16; ++i) {
    vals[i] = xr[g * 128 + s * 16 + i];
    amax = fmaxf(amax, fabsf(vals[i]));
  }
  #pragma unroll
  for (int m = 1; m < 8; m <<= 1) amax = fmaxf(amax, __shfl_xor(amax, m, 64));
  float scale = amax / 6.0f;
  if (scale == 0.f) scale = 1.f;
  const float rs = 1.0f / scale;
  #pragma unroll
  for (int i = 0; i < 16; ++i) {
    float xs = vals[i] * rs;
    xq[g * 128 + s * 16 + i] = copysignf(snap(fabsf(xs)), xs) * scale;
  }
  __syncthreads();
  #pragma unroll
  for (int i = 0; i < 4; ++i) {
    const int o = i * 256 + t;
    const float* wrow = w + (size_t)o * K_DIM;
    float acc = 0.f;
    for (int k = 0; k < K_DIM; k += 4) {
      float4 wv = *reinterpret_cast<const float4*>(wrow + k);
      acc += xq[k] * wv.x + xq[k + 1] * wv.y + xq[k + 2] * wv.z + xq[k + 3] * wv.w;
    }
    out[(size_t)row * N_DIM + o] = acc + bias[o];
  }
}

extern "C" void kernel_launch(void* const* d_in, const int* in_sizes, int n_in,
                              void* d_out, int out_size, void* d_ws, size_t ws_size,
                              hipStream_t stream) {
  const float* x    = (const float*)d_in[0];
  const float* wgt  = (const float*)d_in[1];
  const float* bias = (const float*)d_in[2];
  float* out = (float*)d_out;

  const size_t deq_bytes = (size_t)M_DIM * K_DIM * 2;
  const size_t wb_bytes  = (size_t)N_DIM * K_DIM * 2;
  if (ws_size >= deq_bytes + wb_bytes) {
    ushort_t* deq = (ushort_t*)d_ws;
    ushort_t* wb  = (ushort_t*)((char*)d_ws + deq_bytes);
    quant_kernel<<<(M_DIM * (K_DIM / 128)) / 16, 256, 0, stream>>>(x, deq);
    wconv_kernel<<<1024, 256, 0, stream>>>(wgt, wb);
    gemm256<<<dim3(N_DIM / 256, M_DIM / 256), 512, 0, stream>>>(deq, wb, bias, out);
  } else {
    fused_naive<<<M_DIM, 256, 0, stream>>>(x, wgt, bias, out);
  }
}